// Round 2
// baseline (198.169 us; speedup 1.0000x reference)
//
#include <hip/hip_runtime.h>

#define NTOK 2048
#define BATCH 2
#define FIN 128
#define FEMB 64

typedef __attribute__((ext_vector_type(8))) short short8;
typedef __attribute__((ext_vector_type(4))) float floatx4;

#define MFMA_B16(a, b, c) __builtin_amdgcn_mfma_f32_16x16x32_bf16((a), (b), (c), 0, 0, 0)

// f32 -> bf16 bits (RNE)
static __device__ __forceinline__ unsigned short f2bf_bits(float f) {
    unsigned u = __float_as_uint(f);
    unsigned r = u + 0x7FFFu + ((u >> 16) & 1u);
    return (unsigned short)(r >> 16);
}
static __device__ __forceinline__ float bfbits2f(unsigned short h) {
    return __uint_as_float(((unsigned)h) << 16);
}

// ---------------- P0: xbf = bf16(x), 524288 elems ---------------------------
__global__ void k_prep_x(const float* __restrict__ x, unsigned short* __restrict__ xbf) {
    int t = blockIdx.x * 256 + threadIdx.x;          // 131072 threads, 4 elems each
    float4 v = ((const float4*)x)[t];
    unsigned short h[4] = {f2bf_bits(v.x), f2bf_bits(v.y), f2bf_bits(v.z), f2bf_bits(v.w)};
    ((uint2*)xbf)[t] = *(uint2*)h;
}

// ---------------- P1: WT[f][k] = bf16(W[k][f])  (64x128 <- 128x64) ----------
__global__ void k_transpose_w(const float* __restrict__ W, unsigned short* __restrict__ WT) {
    int t = blockIdx.x * 256 + threadIdx.x;          // 8192 elements
    int k = t >> 6, f = t & 63;
    WT[f * FIN + k] = f2bf_bits(W[t]);
}

// ---------------- K1: XwT[64][4096] = WT(64x128) @ xbf^T(128x4096) ----------
#define K1S 152   // 128 + 24 -> 2-way-free LDS banks, 16B aligned rows
__global__ __launch_bounds__(256) void k_gemm_xwT(const unsigned short* __restrict__ xbf,
                                                  const unsigned short* __restrict__ WT,
                                                  unsigned short* __restrict__ XwT) {
    __shared__ unsigned short As[64 * K1S];
    __shared__ unsigned short Bs[64 * K1S];
    int t = threadIdx.x;
    int n0 = blockIdx.x * 64;   // token tile
#pragma unroll
    for (int c = 0; c < 4; ++c) {
        int e = c * 2048 + t * 8;
        int row = e >> 7, col = e & 127;
        *(uint4*)&As[row * K1S + col] = *(const uint4*)&WT[row * FIN + col];
        *(uint4*)&Bs[row * K1S + col] = *(const uint4*)&xbf[(size_t)(n0 + row) * FIN + col];
    }
    __syncthreads();
    int w = t >> 6, l = t & 63, lm = l & 15, lq = l >> 4;
    floatx4 acc[4] = {};
#pragma unroll
    for (int kk = 0; kk < 128; kk += 32) {
        short8 a = *(const short8*)&As[(w * 16 + lm) * K1S + kk + lq * 8];
#pragma unroll
        for (int ct = 0; ct < 4; ++ct) {
            short8 b = *(const short8*)&Bs[(ct * 16 + lm) * K1S + kk + lq * 8];
            acc[ct] = MFMA_B16(a, b, acc[ct]);
        }
    }
#pragma unroll
    for (int ct = 0; ct < 4; ++ct)
#pragma unroll
        for (int r = 0; r < 4; ++r) {
            int f = w * 16 + lq * 4 + r;
            int tok = n0 + ct * 16 + lm;
            XwT[(size_t)f * (BATCH * NTOK) + tok] = f2bf_bits(acc[ct][r]);
        }
}

// ---------------- K2: x_emb = relu(A @ Xw + b) -> f32 out -------------------
// A staged f32 -> bf16 inline. M-tile 32, K-tile 64. grid (64, B).
#define K2S 88    // 64 + 24
__global__ __launch_bounds__(256) void k_gemm_xemb(const float* __restrict__ A,
                                                   const unsigned short* __restrict__ XwT,
                                                   const float* __restrict__ bvec,
                                                   float* __restrict__ xemb_out) {
    __shared__ unsigned short As[32 * K2S];
    __shared__ unsigned short Bs[64 * K2S];
    int t = threadIdx.x;
    int m0 = blockIdx.x * 32, b = blockIdx.y;
    const float* Ab = A + (size_t)b * NTOK * NTOK;
    int w = t >> 6, l = t & 63, lm = l & 15, lq = l >> 4;
    int rt = w & 1, c0 = (w >> 1) * 2;
    floatx4 acc[2] = {};
    for (int k0 = 0; k0 < NTOK; k0 += 64) {
        __syncthreads();
        {
            int e = t * 8;
            int row = e >> 6, col = e & 63;
            const float* src = &Ab[(size_t)(m0 + row) * NTOK + k0 + col];
            float4 f0 = *(const float4*)src;
            float4 f1 = *(const float4*)(src + 4);
            unsigned short h[8] = {f2bf_bits(f0.x), f2bf_bits(f0.y), f2bf_bits(f0.z),
                                   f2bf_bits(f0.w), f2bf_bits(f1.x), f2bf_bits(f1.y),
                                   f2bf_bits(f1.z), f2bf_bits(f1.w)};
            *(uint4*)&As[row * K2S + col] = *(uint4*)h;
#pragma unroll
            for (int c = 0; c < 2; ++c) {
                int e2 = c * 2048 + t * 8;
                int fr = e2 >> 6, kc = e2 & 63;
                *(uint4*)&Bs[fr * K2S + kc] =
                    *(const uint4*)&XwT[(size_t)fr * (BATCH * NTOK) + b * NTOK + k0 + kc];
            }
        }
        __syncthreads();
#pragma unroll
        for (int kk = 0; kk < 64; kk += 32) {
            short8 a = *(const short8*)&As[(rt * 16 + lm) * K2S + kk + lq * 8];
#pragma unroll
            for (int cc = 0; cc < 2; ++cc) {
                short8 bb = *(const short8*)&Bs[((c0 + cc) * 16 + lm) * K2S + kk + lq * 8];
                acc[cc] = MFMA_B16(a, bb, acc[cc]);
            }
        }
    }
#pragma unroll
    for (int cc = 0; cc < 2; ++cc) {
        int f = (c0 + cc) * 16 + lm;
        float bias = bvec[f];
#pragma unroll
        for (int r = 0; r < 4; ++r) {
            int m = m0 + rt * 16 + lq * 4 + r;
            float v = fmaxf(acc[cc][r] + bias, 0.0f);
            xemb_out[(size_t)b * NTOK * FEMB + (size_t)m * FEMB + f] = v;
        }
    }
}

// ---------------- K3a: centroid sums (divide by N at readers) ---------------
__global__ void k_centroid(const float* __restrict__ xemb, float* __restrict__ cent) {
    int seg = blockIdx.x, b = blockIdx.y;
    int t = threadIdx.x, f = t & 63, rg = t >> 6;
    const float* p = xemb + (size_t)b * NTOK * FEMB + (size_t)(seg * 256 + rg * 64) * FEMB + f;
    float s = 0.f;
    for (int i = 0; i < 64; ++i) s += p[i * FEMB];
    __shared__ float red[4][64];
    red[rg][f] = s;
    __syncthreads();
    if (rg == 0)
        atomicAdd(&cent[b * 64 + f], red[0][f] + red[1][f] + red[2][f] + red[3][f]);
}

// ---------------- K3b: global max |x_emb - centroid| ------------------------
__global__ void k_maxabs(const float* __restrict__ xemb, const float* __restrict__ cent,
                         unsigned* __restrict__ mx) {
    int gid = blockIdx.x * 256 + threadIdx.x;
    float m = 0.f;
    for (int idx = gid; idx < BATCH * NTOK * FEMB; idx += 256 * 256) {
        int b = idx >> 17, f = idx & 63;
        float c = cent[b * 64 + f] * (1.0f / NTOK);
        m = fmaxf(m, fabsf(xemb[idx] - c));
    }
#pragma unroll
    for (int off = 32; off; off >>= 1) m = fmaxf(m, __shfl_xor(m, off, 64));
    if ((threadIdx.x & 63) == 0) atomicMax(mx, __float_as_uint(m));  // m >= 0
}

// ---------------- K4: xs (bf16) and sq = sum(bf16(xs)^2) --------------------
__global__ void k_xs_sq(const float* __restrict__ xemb, const float* __restrict__ cent,
                        const unsigned* __restrict__ mx,
                        unsigned short* __restrict__ xs, float* __restrict__ sq) {
    int t = threadIdx.x;
    int row = blockIdx.x * 4 + (t >> 6);   // global row 0..4095
    int f = t & 63;
    int b = row >> 11;
    float scale = 0.9f / __uint_as_float(*mx);
    float c = cent[b * 64 + f] * (1.0f / NTOK);
    float v = (xemb[(size_t)row * FEMB + f] - c) * scale;
    unsigned short hb = f2bf_bits(v);
    xs[(size_t)row * FEMB + f] = hb;
    float d = bfbits2f(hb);
    float s = d * d;
#pragma unroll
    for (int off = 32; off; off >>= 1) s += __shfl_xor(s, off, 64);
    if (f == 0) sq[row] = s;
}

// ---------------- K5: Gram + distances + sigmoid adjacency -> f32 -----------
#define K5S 88
__global__ __launch_bounds__(256) void k_adj(const unsigned short* __restrict__ xs,
                                             const float* __restrict__ sq,
                                             const float* __restrict__ temp,
                                             const float* __restrict__ thr,
                                             float* __restrict__ wout) {
    __shared__ unsigned short As[128 * K5S];
    __shared__ unsigned short Bs[128 * K5S];
    int t = threadIdx.x;
    int m0 = blockIdx.x * 128, n0 = blockIdx.y * 128, b = blockIdx.z;
    const unsigned short* xb = xs + (size_t)b * NTOK * FEMB;
#pragma unroll
    for (int c = 0; c < 4; ++c) {
        int e = c * 2048 + t * 8;
        int row = e >> 6, col = e & 63;
        *(uint4*)&As[row * K5S + col] = *(const uint4*)&xb[(size_t)(m0 + row) * FEMB + col];
        *(uint4*)&Bs[row * K5S + col] = *(const uint4*)&xb[(size_t)(n0 + row) * FEMB + col];
    }
    __syncthreads();
    int w = t >> 6, l = t & 63, lm = l & 15, lq = l >> 4;
    floatx4 acc[2][8] = {};
#pragma unroll
    for (int kk = 0; kk < 64; kk += 32) {
        short8 a0 = *(const short8*)&As[((w * 2 + 0) * 16 + lm) * K5S + kk + lq * 8];
        short8 a1 = *(const short8*)&As[((w * 2 + 1) * 16 + lm) * K5S + kk + lq * 8];
#pragma unroll
        for (int ct = 0; ct < 8; ++ct) {
            short8 bb = *(const short8*)&Bs[(ct * 16 + lm) * K5S + kk + lq * 8];
            acc[0][ct] = MFMA_B16(a0, bb, acc[0][ct]);
            acc[1][ct] = MFMA_B16(a1, bb, acc[1][ct]);
        }
    }
    float tval = temp[0];
    float ath = fabsf(thr[0]);
    float sqm[2][4], sqn[8];
#pragma unroll
    for (int rt = 0; rt < 2; ++rt)
#pragma unroll
        for (int r = 0; r < 4; ++r)
            sqm[rt][r] = sq[b * NTOK + m0 + (w * 2 + rt) * 16 + lq * 4 + r];
#pragma unroll
    for (int ct = 0; ct < 8; ++ct) sqn[ct] = sq[b * NTOK + n0 + ct * 16 + lm];
    float* wob = wout + (size_t)b * NTOK * NTOK;
#pragma unroll
    for (int rt = 0; rt < 2; ++rt)
#pragma unroll
        for (int r = 0; r < 4; ++r) {
            int m = m0 + (w * 2 + rt) * 16 + lq * 4 + r;
#pragma unroll
            for (int ct = 0; ct < 8; ++ct) {
                float g = acc[rt][ct][r];
                float D = fmaxf(sqm[rt][r] + sqn[ct] - 2.0f * g, 0.0f);
                float z = tval * (ath - D);
                float wgt = 1.0f / (1.0f + __expf(-z));
                wob[(size_t)m * NTOK + n0 + ct * 16 + lm] = wgt;
            }
        }
}

// ---------------- K6: edge_index (rows then cols) as f32 --------------------
__global__ void k_edges(float* __restrict__ eout) {
    long i = (long)blockIdx.x * 256 + threadIdx.x;   // 4,194,304 threads
    long base = i * 4;                               // 16,777,216 f32 elements
    float4 v;
    if (base < 8388608L) {                           // rows: idx // N (const over 4)
        float r = (float)(base >> 11);
        v.x = r; v.y = r; v.z = r; v.w = r;
    } else {                                         // cols: idx % N + N*batch
        long rel = base - 8388608L;
        int c0 = (int)(rel & 2047);                  // multiple of 4 -> no wrap
        int add = ((int)(rel >> 22)) << 11;
        v.x = (float)(c0 + 0 + add);
        v.y = (float)(c0 + 1 + add);
        v.z = (float)(c0 + 2 + add);
        v.w = (float)(c0 + 3 + add);
    }
    *(float4*)&eout[base] = v;
}

extern "C" void kernel_launch(void* const* d_in, const int* in_sizes, int n_in,
                              void* d_out, int out_size, void* d_ws, size_t ws_size,
                              hipStream_t stream) {
    const float* x    = (const float*)d_in[0];   // [2,2048,128] f32
    const float* A    = (const float*)d_in[1];   // [2,2048,2048] f32
    const float* W    = (const float*)d_in[2];   // [128,64] f32
    const float* bvec = (const float*)d_in[3];   // [64] f32
    const float* temp = (const float*)d_in[4];   // scalar f32
    const float* thr  = (const float*)d_in[5];   // scalar f32
    float* out = (float*)d_out;                  // 25,427,968 f32: x_emb | edge_index | weights
    char* ws = (char*)d_ws;

    unsigned short* XwT = (unsigned short*)(ws + 0);        // 64x4096 bf16  (512 KB)
    unsigned short* xbf = (unsigned short*)(ws + 524288);   // 4096x128 bf16 (1 MB)
    unsigned short* WT  = (unsigned short*)(ws + 1572864);  // 64x128 bf16   (16 KB)
    float*          cent= (float*)(ws + 1589248);           // 128 f32
    unsigned*       mx  = (unsigned*)(ws + 1589760);        // 1 u32
    unsigned short* xs  = (unsigned short*)(ws + 1589776);  // 4096x64 bf16  (512 KB)
    float*          sq  = (float*)(ws + 2114064);           // 4096 f32

    float* xemb_out = out;                       // [0, 262144)
    float* edge_out = out + 262144;              // [262144, 17039360)
    float* wgt_out  = out + 262144 + 16777216;   // [17039360, 25427968)

    hipMemsetAsync(ws + 1589248, 0, 516, stream);           // cent + mx

    k_prep_x<<<512, 256, 0, stream>>>(x, xbf);
    k_transpose_w<<<32, 256, 0, stream>>>(W, WT);
    k_gemm_xwT<<<64, 256, 0, stream>>>(xbf, WT, XwT);
    k_gemm_xemb<<<dim3(64, 2), 256, 0, stream>>>(A, XwT, bvec, xemb_out);
    k_centroid<<<dim3(8, 2), 256, 0, stream>>>(xemb_out, cent);
    k_maxabs<<<256, 256, 0, stream>>>(xemb_out, cent, mx);
    k_xs_sq<<<1024, 256, 0, stream>>>(xemb_out, cent, mx, xs, sq);
    k_adj<<<dim3(16, 16, 2), 256, 0, stream>>>(xs, sq, temp, thr, wgt_out);
    k_edges<<<16384, 256, 0, stream>>>(edge_out);
}

// Round 3
// 175.970 us; speedup vs baseline: 1.1261x; 1.1261x over previous
//
#include <hip/hip_runtime.h>

#define NTOK 2048
#define BATCH 2
#define FIN 128
#define FEMB 64

typedef __attribute__((ext_vector_type(8))) short short8;
typedef __attribute__((ext_vector_type(4))) float floatx4;

#define MFMA_B16(a, b, c) __builtin_amdgcn_mfma_f32_16x16x32_bf16((a), (b), (c), 0, 0, 0)

// f32 -> bf16 bits (RNE)
static __device__ __forceinline__ unsigned short f2bf_bits(float f) {
    unsigned u = __float_as_uint(f);
    unsigned r = u + 0x7FFFu + ((u >> 16) & 1u);
    return (unsigned short)(r >> 16);
}
static __device__ __forceinline__ float bfbits2f(unsigned short h) {
    return __uint_as_float(((unsigned)h) << 16);
}

// ============ K1: XwT[64][4096] = bf16(W)^T (64x128) @ bf16(x)^T (128x4096) =
// Fused: W transpose+convert and x convert happen during LDS staging.
#define K1S 152   // 128+24 shorts: rows differ by 12 banks -> <=2-way, free
__global__ __launch_bounds__(256) void k_gemm_xwT(const float* __restrict__ x,
                                                  const float* __restrict__ W,
                                                  unsigned short* __restrict__ XwT) {
    __shared__ unsigned short As[64 * K1S];   // WT[f][k]
    __shared__ unsigned short Bs[64 * K1S];   // x rows (tokens) [n][k]
    int t = threadIdx.x;
    int n0 = blockIdx.x * 64;
    // W: 128x64 f32 (32 KB, L2-resident after first block) -> transposed bf16
#pragma unroll
    for (int c = 0; c < 32; ++c) {
        int idx = c * 256 + t;
        int k = idx >> 6, f = idx & 63;
        As[f * K1S + k] = f2bf_bits(W[idx]);
    }
    // x tile: 64 tokens x 128 feat f32 -> bf16
#pragma unroll
    for (int c = 0; c < 4; ++c) {
        int e = c * 2048 + t * 8;
        int row = e >> 7, col = e & 127;
        const float* src = &x[(size_t)(n0 + row) * FIN + col];
        float4 f0 = *(const float4*)src;
        float4 f1 = *(const float4*)(src + 4);
        unsigned short h[8] = {f2bf_bits(f0.x), f2bf_bits(f0.y), f2bf_bits(f0.z),
                               f2bf_bits(f0.w), f2bf_bits(f1.x), f2bf_bits(f1.y),
                               f2bf_bits(f1.z), f2bf_bits(f1.w)};
        *(uint4*)&Bs[row * K1S + col] = *(uint4*)h;
    }
    __syncthreads();
    int w = t >> 6, l = t & 63, lm = l & 15, lq = l >> 4;
    floatx4 acc[4] = {};
#pragma unroll
    for (int kk = 0; kk < 128; kk += 32) {
        short8 a = *(const short8*)&As[(w * 16 + lm) * K1S + kk + lq * 8];
#pragma unroll
        for (int ct = 0; ct < 4; ++ct) {
            short8 b = *(const short8*)&Bs[(ct * 16 + lm) * K1S + kk + lq * 8];
            acc[ct] = MFMA_B16(a, b, acc[ct]);
        }
    }
#pragma unroll
    for (int ct = 0; ct < 4; ++ct)
#pragma unroll
        for (int r = 0; r < 4; ++r) {
            int f = w * 16 + lq * 4 + r;
            int tok = n0 + ct * 16 + lm;
            XwT[(size_t)f * (BATCH * NTOK) + tok] = f2bf_bits(acc[ct][r]);
        }
}

// ============ K2: x_emb = relu(A @ Xw + b) -> f32 out; fused centroid atomics
// M-tile 16, K-tile 256, grid (128, B) = 256 blocks, 8 K-iterations.
#define S2 280    // 256+24 shorts: same 12-dword-bank row offset, free
__global__ __launch_bounds__(256) void k_gemm_xemb(const float* __restrict__ A,
                                                   const unsigned short* __restrict__ XwT,
                                                   const float* __restrict__ bvec,
                                                   float* __restrict__ xemb_out,
                                                   float* __restrict__ cent) {
    __shared__ unsigned short As[16 * S2];
    __shared__ unsigned short Bs[64 * S2];
    int t = threadIdx.x;
    int m0 = blockIdx.x * 16, b = blockIdx.y;
    const float* Ab = A + (size_t)b * NTOK * NTOK;
    int w = t >> 6, l = t & 63, lm = l & 15, lq = l >> 4;
    floatx4 acc = {};
    for (int k0 = 0; k0 < NTOK; k0 += 256) {
        __syncthreads();
        {
            // A tile: 16 x 256 f32 -> bf16 (16 elems/thread)
            int row = t >> 4, colb = (t & 15) * 16;
            const float* src = &Ab[(size_t)(m0 + row) * NTOK + k0 + colb];
            unsigned short h[16];
#pragma unroll
            for (int i = 0; i < 4; ++i) {
                float4 v = *(const float4*)(src + i * 4);
                h[i * 4 + 0] = f2bf_bits(v.x);
                h[i * 4 + 1] = f2bf_bits(v.y);
                h[i * 4 + 2] = f2bf_bits(v.z);
                h[i * 4 + 3] = f2bf_bits(v.w);
            }
            *(uint4*)&As[row * S2 + colb] = *(uint4*)&h[0];
            *(uint4*)&As[row * S2 + colb + 8] = *(uint4*)&h[8];
            // B tile: 64 feats x 256 k bf16 (64 elems/thread, L2-resident XwT)
            int f = t >> 2, cb = (t & 3) * 64;
            const unsigned short* bs = &XwT[(size_t)f * (BATCH * NTOK) + b * NTOK + k0 + cb];
#pragma unroll
            for (int i = 0; i < 8; ++i)
                *(uint4*)&Bs[f * S2 + cb + i * 8] = *(const uint4*)(bs + i * 8);
        }
        __syncthreads();
#pragma unroll
        for (int kk = 0; kk < 256; kk += 32) {
            short8 a = *(const short8*)&As[lm * S2 + kk + lq * 8];
            short8 bb = *(const short8*)&Bs[(w * 16 + lm) * S2 + kk + lq * 8];
            acc = MFMA_B16(a, bb, acc);
        }
    }
    int f = w * 16 + lm;
    float bias = bvec[f];
    float s = 0.f;
#pragma unroll
    for (int r = 0; r < 4; ++r) {
        int m = m0 + lq * 4 + r;
        float v = fmaxf(acc[r] + bias, 0.0f);
        xemb_out[(size_t)b * NTOK * FEMB + (size_t)m * FEMB + f] = v;
        s += v;
    }
    // reduce the 16-row tile's column sums across the 4 quads -> centroid
    s += __shfl_xor(s, 16, 64);
    s += __shfl_xor(s, 32, 64);
    if (lq == 0) atomicAdd(&cent[b * 64 + f], s);
}

// ============ K3: global max |x_emb - centroid|, float4 per thread ==========
__global__ void k_maxabs(const float* __restrict__ xemb, const float* __restrict__ cent,
                         unsigned* __restrict__ mx) {
    int gid = blockIdx.x * 256 + threadIdx.x;   // 65536 threads x 4 elems
    int i4 = gid * 4;
    int b = i4 >> 17, f = i4 & 63;
    float4 v = *(const float4*)&xemb[i4];
    float4 c = *(const float4*)&cent[b * 64 + f];
    float m = fmaxf(fmaxf(fabsf(v.x - c.x * (1.0f / NTOK)), fabsf(v.y - c.y * (1.0f / NTOK))),
                    fmaxf(fabsf(v.z - c.z * (1.0f / NTOK)), fabsf(v.w - c.w * (1.0f / NTOK))));
#pragma unroll
    for (int off = 32; off; off >>= 1) m = fmaxf(m, __shfl_xor(m, off, 64));
    if ((threadIdx.x & 63) == 0) atomicMax(mx, __float_as_uint(m));  // m >= 0
}

// ============ K4: xs (bf16) and sq = sum(bf16(xs)^2) ========================
// sq from the SAME rounded xs that feeds the Gram MFMA -> diagonal D == 0.
__global__ void k_xs_sq(const float* __restrict__ xemb, const float* __restrict__ cent,
                        const unsigned* __restrict__ mx,
                        unsigned short* __restrict__ xs, float* __restrict__ sq) {
    int t = threadIdx.x;
    int row = blockIdx.x * 4 + (t >> 6);   // global row 0..4095
    int f = t & 63;
    int b = row >> 11;
    float scale = 0.9f / __uint_as_float(*mx);
    float c = cent[b * 64 + f] * (1.0f / NTOK);
    float v = (xemb[(size_t)row * FEMB + f] - c) * scale;
    unsigned short hb = f2bf_bits(v);
    xs[(size_t)row * FEMB + f] = hb;
    float d = bfbits2f(hb);
    float s = d * d;
#pragma unroll
    for (int off = 32; off; off >>= 1) s += __shfl_xor(s, off, 64);
    if (f == 0) sq[row] = s;
}

// ============ K5: adjacency (z<2) + edge_index (z>=2) fused =================
// adj: 128x128 tile, K=64 single shot, grid z 0..1; edges: 512 pure-write blocks.
#define K5S 88
__global__ __launch_bounds__(256) void k_adj_edges(const unsigned short* __restrict__ xs,
                                                   const float* __restrict__ sq,
                                                   const float* __restrict__ temp,
                                                   const float* __restrict__ thr,
                                                   float* __restrict__ wout,
                                                   float* __restrict__ eout) {
    int z = blockIdx.z;
    if (z >= 2) {   // ---- edge_index: 16,777,216 f32 over 512 blocks ----
        int eb = (z - 2) * 256 + blockIdx.y * 16 + blockIdx.x;
        long base0 = (long)eb * 32768 + threadIdx.x * 4;
#pragma unroll
        for (int j = 0; j < 32; ++j) {
            long g = base0 + (long)j * 1024;
            float4 v;
            if (g < 8388608L) {                  // rows: idx // N (const over 4)
                float r = (float)(g >> 11);
                v.x = r; v.y = r; v.z = r; v.w = r;
            } else {                             // cols: idx % N + N*batch
                long rel = g - 8388608L;
                int c0 = (int)(rel & 2047);      // 4-aligned, no wrap
                int add = ((int)(rel >> 22)) << 11;
                v.x = (float)(c0 + 0 + add);
                v.y = (float)(c0 + 1 + add);
                v.z = (float)(c0 + 2 + add);
                v.w = (float)(c0 + 3 + add);
            }
            *(float4*)&eout[g] = v;
        }
        return;
    }
    // ---- adjacency ----
    __shared__ unsigned short As[128 * K5S];
    __shared__ unsigned short Bs[128 * K5S];
    int t = threadIdx.x;
    int m0 = blockIdx.x * 128, n0 = blockIdx.y * 128, b = z;
    const unsigned short* xb = xs + (size_t)b * NTOK * FEMB;
#pragma unroll
    for (int c = 0; c < 4; ++c) {
        int e = c * 2048 + t * 8;
        int row = e >> 6, col = e & 63;
        *(uint4*)&As[row * K5S + col] = *(const uint4*)&xb[(size_t)(m0 + row) * FEMB + col];
        *(uint4*)&Bs[row * K5S + col] = *(const uint4*)&xb[(size_t)(n0 + row) * FEMB + col];
    }
    __syncthreads();
    int w = t >> 6, l = t & 63, lm = l & 15, lq = l >> 4;
    floatx4 acc[2][8] = {};
#pragma unroll
    for (int kk = 0; kk < 64; kk += 32) {
        short8 a0 = *(const short8*)&As[((w * 2 + 0) * 16 + lm) * K5S + kk + lq * 8];
        short8 a1 = *(const short8*)&As[((w * 2 + 1) * 16 + lm) * K5S + kk + lq * 8];
#pragma unroll
        for (int ct = 0; ct < 8; ++ct) {
            short8 bb = *(const short8*)&Bs[(ct * 16 + lm) * K5S + kk + lq * 8];
            acc[0][ct] = MFMA_B16(a0, bb, acc[0][ct]);
            acc[1][ct] = MFMA_B16(a1, bb, acc[1][ct]);
        }
    }
    float tval = temp[0];
    float ath = fabsf(thr[0]);
    float sqm[2][4], sqn[8];
#pragma unroll
    for (int rt = 0; rt < 2; ++rt)
#pragma unroll
        for (int r = 0; r < 4; ++r)
            sqm[rt][r] = sq[b * NTOK + m0 + (w * 2 + rt) * 16 + lq * 4 + r];
#pragma unroll
    for (int ct = 0; ct < 8; ++ct) sqn[ct] = sq[b * NTOK + n0 + ct * 16 + lm];
    float* wob = wout + (size_t)b * NTOK * NTOK;
#pragma unroll
    for (int rt = 0; rt < 2; ++rt)
#pragma unroll
        for (int r = 0; r < 4; ++r) {
            int m = m0 + (w * 2 + rt) * 16 + lq * 4 + r;
#pragma unroll
            for (int ct = 0; ct < 8; ++ct) {
                float g = acc[rt][ct][r];
                float D = fmaxf(sqm[rt][r] + sqn[ct] - 2.0f * g, 0.0f);
                float z2 = tval * (ath - D);
                float wgt = 1.0f / (1.0f + __expf(-z2));
                wob[(size_t)m * NTOK + n0 + ct * 16 + lm] = wgt;
            }
        }
}

extern "C" void kernel_launch(void* const* d_in, const int* in_sizes, int n_in,
                              void* d_out, int out_size, void* d_ws, size_t ws_size,
                              hipStream_t stream) {
    const float* x    = (const float*)d_in[0];   // [2,2048,128] f32
    const float* A    = (const float*)d_in[1];   // [2,2048,2048] f32
    const float* W    = (const float*)d_in[2];   // [128,64] f32
    const float* bvec = (const float*)d_in[3];   // [64] f32
    const float* temp = (const float*)d_in[4];   // scalar f32
    const float* thr  = (const float*)d_in[5];   // scalar f32
    float* out = (float*)d_out;                  // x_emb | edge_index | weights
    char* ws = (char*)d_ws;

    unsigned short* XwT = (unsigned short*)(ws + 0);        // 64x4096 bf16 (512 KB)
    float*          cent= (float*)(ws + 524288);            // 128 f32
    unsigned*       mx  = (unsigned*)(ws + 524800);         // 1 u32
    unsigned short* xs  = (unsigned short*)(ws + 524816);   // 4096x64 bf16 (512 KB)
    float*          sq  = (float*)(ws + 1049104);           // 4096 f32

    float* xemb_out = out;                       // [0, 262144)
    float* edge_out = out + 262144;              // [262144, 17039360)
    float* wgt_out  = out + 262144 + 16777216;   // [17039360, 25427968)

    hipMemsetAsync(ws + 524288, 0, 520, stream); // cent + mx

    k_gemm_xwT<<<64, 256, 0, stream>>>(x, W, XwT);
    k_gemm_xemb<<<dim3(128, 2), 256, 0, stream>>>(A, XwT, bvec, xemb_out, cent);
    k_maxabs<<<256, 256, 0, stream>>>(xemb_out, cent, mx);
    k_xs_sq<<<1024, 256, 0, stream>>>(xemb_out, cent, mx, xs, sq);
    k_adj_edges<<<dim3(16, 16, 4), 256, 0, stream>>>(xs, sq, temp, thr, wgt_out, edge_out);
}

// Round 4
// 169.494 us; speedup vs baseline: 1.1692x; 1.0382x over previous
//
#include <hip/hip_runtime.h>

#define NTOK 2048
#define BATCH 2
#define FIN 128
#define FEMB 64

typedef __attribute__((ext_vector_type(8))) short short8;
typedef __attribute__((ext_vector_type(4))) float floatx4;

#define MFMA_B16(a, b, c) __builtin_amdgcn_mfma_f32_16x16x32_bf16((a), (b), (c), 0, 0, 0)

// f32 -> bf16 bits (RNE)
static __device__ __forceinline__ unsigned short f2bf_bits(float f) {
    unsigned u = __float_as_uint(f);
    unsigned r = u + 0x7FFFu + ((u >> 16) & 1u);
    return (unsigned short)(r >> 16);
}
static __device__ __forceinline__ float bfbits2f(unsigned short h) {
    return __uint_as_float(((unsigned)h) << 16);
}

// ============ K1: XwT[64][4096] = bf16(W)^T (64x128) @ bf16(x)^T (128x4096) =
// n-tile 32, grid 128. Block 0 also zero-inits cent+mx (runs before K2).
#define K1S 152   // 128+24 shorts: rows differ by 12 dword-banks -> <=2-way, free
__global__ __launch_bounds__(256) void k_gemm_xwT(const float* __restrict__ x,
                                                  const float* __restrict__ W,
                                                  unsigned short* __restrict__ XwT,
                                                  unsigned* __restrict__ centmx) {
    __shared__ unsigned short As[64 * K1S];   // WT[f][k]
    __shared__ unsigned short Bs[32 * K1S];   // x token rows [n][k]
    int t = threadIdx.x;
    int n0 = blockIdx.x * 32;
    if (blockIdx.x == 0 && t < 129) centmx[t] = 0;   // cent[128] + mx[1]
    // W: 128x64 f32 (L2-resident) -> transposed bf16 in LDS
#pragma unroll
    for (int c = 0; c < 32; ++c) {
        int idx = c * 256 + t;
        int k = idx >> 6, f = idx & 63;
        As[f * K1S + k] = f2bf_bits(W[idx]);
    }
    // x tile: 32 tokens x 128 feat f32 -> bf16
#pragma unroll
    for (int c = 0; c < 2; ++c) {
        int e = c * 2048 + t * 8;
        int row = e >> 7, col = e & 127;
        const float* src = &x[(size_t)(n0 + row) * FIN + col];
        float4 f0 = *(const float4*)src;
        float4 f1 = *(const float4*)(src + 4);
        unsigned short h[8] = {f2bf_bits(f0.x), f2bf_bits(f0.y), f2bf_bits(f0.z),
                               f2bf_bits(f0.w), f2bf_bits(f1.x), f2bf_bits(f1.y),
                               f2bf_bits(f1.z), f2bf_bits(f1.w)};
        *(uint4*)&Bs[row * K1S + col] = *(uint4*)h;
    }
    __syncthreads();
    int w = t >> 6, l = t & 63, lm = l & 15, lq = l >> 4;
    floatx4 acc[2] = {};
#pragma unroll
    for (int kk = 0; kk < 128; kk += 32) {
        short8 a = *(const short8*)&As[(w * 16 + lm) * K1S + kk + lq * 8];
#pragma unroll
        for (int ct = 0; ct < 2; ++ct) {
            short8 b = *(const short8*)&Bs[(ct * 16 + lm) * K1S + kk + lq * 8];
            acc[ct] = MFMA_B16(a, b, acc[ct]);
        }
    }
#pragma unroll
    for (int ct = 0; ct < 2; ++ct)
#pragma unroll
        for (int r = 0; r < 4; ++r) {
            int f = w * 16 + lq * 4 + r;
            int tok = n0 + ct * 16 + lm;
            XwT[(size_t)f * (BATCH * NTOK) + tok] = f2bf_bits(acc[ct][r]);
        }
}

// ============ K2: x_emb = relu(A @ Xw + b); LDS-free streaming GEMM =========
// 512 thr (8 waves), each wave owns K-range w*256..+256; no barriers in loop.
// Epilogue: cross-wave f32 reduce in LDS, emit xemb f32 + bf16, q rowsums,
// centroid atomics. grid (128, 2).
#define RP 66     // 64+2 f32: wave-partial row stride (2-way banks, free)
__global__ __launch_bounds__(512) void k_gemm_xemb(const float* __restrict__ A,
                                                   const unsigned short* __restrict__ XwT,
                                                   const float* __restrict__ bvec,
                                                   float* __restrict__ xemb_out,
                                                   unsigned short* __restrict__ xebf,
                                                   float* __restrict__ q,
                                                   float* __restrict__ cent) {
    __shared__ float red[8][16][RP];   // 33.8 KB
    int t = threadIdx.x;
    int m0 = blockIdx.x * 16, b = blockIdx.y;
    int w = t >> 6, l = t & 63, lm = l & 15, lq = l >> 4;
    const float* Arow =
        A + (size_t)b * NTOK * NTOK + (size_t)(m0 + lm) * NTOK + w * 256 + lq * 8;
    const unsigned short* Bbase = XwT + b * NTOK + w * 256 + lq * 8;  // + f*4096
    floatx4 acc[4] = {};
#pragma unroll
    for (int kk = 0; kk < 256; kk += 32) {
        float4 a0 = *(const float4*)(Arow + kk);
        float4 a1 = *(const float4*)(Arow + kk + 4);
        unsigned short h[8] = {f2bf_bits(a0.x), f2bf_bits(a0.y), f2bf_bits(a0.z),
                               f2bf_bits(a0.w), f2bf_bits(a1.x), f2bf_bits(a1.y),
                               f2bf_bits(a1.z), f2bf_bits(a1.w)};
        short8 af = *(short8*)h;
#pragma unroll
        for (int ct = 0; ct < 4; ++ct) {
            short8 bf = *(const short8*)(Bbase + (size_t)(ct * 16 + lm) * (BATCH * NTOK) + kk);
            acc[ct] = MFMA_B16(af, bf, acc[ct]);
        }
    }
#pragma unroll
    for (int ct = 0; ct < 4; ++ct)
#pragma unroll
        for (int r = 0; r < 4; ++r)
            red[w][lq * 4 + r][ct * 16 + lm] = acc[ct][r];
    __syncthreads();
    // thread t: row r = t>>5 (16 rows), cols c0 = (t&31)*2 (+1)
    int r = t >> 5, c0 = (t & 31) * 2;
    float v0 = 0.f, v1 = 0.f;
#pragma unroll
    for (int ww = 0; ww < 8; ++ww) {
        v0 += red[ww][r][c0];
        v1 += red[ww][r][c0 + 1];
    }
    v0 = fmaxf(v0 + bvec[c0], 0.0f);
    v1 = fmaxf(v1 + bvec[c0 + 1], 0.0f);
    size_t o = (size_t)b * NTOK * FEMB + (size_t)(m0 + r) * FEMB + c0;
    *(float2*)&xemb_out[o] = make_float2(v0, v1);
    unsigned short h0 = f2bf_bits(v0), h1 = f2bf_bits(v1);
    *(unsigned*)&xebf[o] = (unsigned)h0 | ((unsigned)h1 << 16);
    float d0 = bfbits2f(h0), d1 = bfbits2f(h1);
    float s = d0 * d0 + d1 * d1;   // row-sumsq partial (2 cols)
#pragma unroll
    for (int off = 16; off; off >>= 1) s += __shfl_xor(s, off, 64);  // 32-lane group
    if ((t & 31) == 0) q[b * NTOK + m0 + r] = s;
    __syncthreads();               // red reads done; reuse red[0] as vb[16][RP]
    red[0][r][c0] = v0;
    red[0][r][c0 + 1] = v1;
    __syncthreads();
    if (t < 64) {
        float cs = 0.f;
#pragma unroll
        for (int rr = 0; rr < 16; ++rr) cs += red[0][rr][t];
        atomicAdd(&cent[b * 64 + t], cs);
    }
}

// ============ K3: global max |x_emb - centroid|, float4 per thread ==========
__global__ void k_maxabs(const float* __restrict__ xemb, const float* __restrict__ cent,
                         unsigned* __restrict__ mx) {
    int gid = blockIdx.x * 256 + threadIdx.x;   // 65536 threads x 4 elems
    int i4 = gid * 4;
    int b = i4 >> 17, f = i4 & 63;
    float4 v = *(const float4*)&xemb[i4];
    float4 c = *(const float4*)&cent[b * 64 + f];
    float m = fmaxf(fmaxf(fabsf(v.x - c.x * (1.0f / NTOK)), fabsf(v.y - c.y * (1.0f / NTOK))),
                    fmaxf(fabsf(v.z - c.z * (1.0f / NTOK)), fabsf(v.w - c.w * (1.0f / NTOK))));
#pragma unroll
    for (int off = 32; off; off >>= 1) m = fmaxf(m, __shfl_xor(m, off, 64));
    if ((threadIdx.x & 63) == 0) atomicMax(mx, __float_as_uint(m));  // m >= 0
}

// ============ K5: adjacency (z<2) + edge_index (z>=2) fused =================
// D = s^2 * relu(q_m + q_n - 2<e_m,e_n>)  (centroid cancels; s = 0.9/mx)
#define K5S 88
__global__ __launch_bounds__(256) void k_adj_edges(const unsigned short* __restrict__ xebf,
                                                   const float* __restrict__ q,
                                                   const unsigned* __restrict__ mx,
                                                   const float* __restrict__ temp,
                                                   const float* __restrict__ thr,
                                                   float* __restrict__ wout,
                                                   float* __restrict__ eout) {
    int z = blockIdx.z;
    if (z >= 2) {   // ---- edge_index: 16,777,216 f32 over 512 blocks ----
        int eb = (z - 2) * 256 + blockIdx.y * 16 + blockIdx.x;
        long base0 = (long)eb * 32768 + threadIdx.x * 4;
#pragma unroll
        for (int j = 0; j < 32; ++j) {
            long g = base0 + (long)j * 1024;
            float4 v;
            if (g < 8388608L) {                  // rows: idx // N (const over 4)
                float rr = (float)(g >> 11);
                v.x = rr; v.y = rr; v.z = rr; v.w = rr;
            } else {                             // cols: idx % N + N*batch
                long rel = g - 8388608L;
                int c0 = (int)(rel & 2047);      // 4-aligned, no wrap
                int add = ((int)(rel >> 22)) << 11;
                v.x = (float)(c0 + 0 + add);
                v.y = (float)(c0 + 1 + add);
                v.z = (float)(c0 + 2 + add);
                v.w = (float)(c0 + 3 + add);
            }
            *(float4*)&eout[g] = v;
        }
        return;
    }
    // ---- adjacency: 128x128 tile, K=64 single shot ----
    __shared__ unsigned short As[128 * K5S];
    __shared__ unsigned short Bs[128 * K5S];
    int t = threadIdx.x;
    int m0 = blockIdx.x * 128, n0 = blockIdx.y * 128, b = z;
    const unsigned short* xb = xebf + (size_t)b * NTOK * FEMB;
#pragma unroll
    for (int c = 0; c < 4; ++c) {
        int e = c * 2048 + t * 8;
        int row = e >> 6, col = e & 63;
        *(uint4*)&As[row * K5S + col] = *(const uint4*)&xb[(size_t)(m0 + row) * FEMB + col];
        *(uint4*)&Bs[row * K5S + col] = *(const uint4*)&xb[(size_t)(n0 + row) * FEMB + col];
    }
    __syncthreads();
    int w = t >> 6, l = t & 63, lm = l & 15, lq = l >> 4;
    floatx4 acc[2][8] = {};
#pragma unroll
    for (int kk = 0; kk < 64; kk += 32) {
        short8 a0 = *(const short8*)&As[((w * 2 + 0) * 16 + lm) * K5S + kk + lq * 8];
        short8 a1 = *(const short8*)&As[((w * 2 + 1) * 16 + lm) * K5S + kk + lq * 8];
#pragma unroll
        for (int ct = 0; ct < 8; ++ct) {
            short8 bb = *(const short8*)&Bs[(ct * 16 + lm) * K5S + kk + lq * 8];
            acc[0][ct] = MFMA_B16(a0, bb, acc[0][ct]);
            acc[1][ct] = MFMA_B16(a1, bb, acc[1][ct]);
        }
    }
    float sc = 0.9f / __uint_as_float(*mx);
    float s2 = sc * sc;
    float tval = temp[0];
    float ath = fabsf(thr[0]);
    float qm[2][4], qn[8];
#pragma unroll
    for (int rt = 0; rt < 2; ++rt)
#pragma unroll
        for (int r = 0; r < 4; ++r)
            qm[rt][r] = q[b * NTOK + m0 + (w * 2 + rt) * 16 + lq * 4 + r];
#pragma unroll
    for (int ct = 0; ct < 8; ++ct) qn[ct] = q[b * NTOK + n0 + ct * 16 + lm];
    float* wob = wout + (size_t)b * NTOK * NTOK;
#pragma unroll
    for (int rt = 0; rt < 2; ++rt)
#pragma unroll
        for (int r = 0; r < 4; ++r) {
            int m = m0 + (w * 2 + rt) * 16 + lq * 4 + r;
#pragma unroll
            for (int ct = 0; ct < 8; ++ct) {
                float g = acc[rt][ct][r];
                float D = s2 * fmaxf(qm[rt][r] + qn[ct] - 2.0f * g, 0.0f);
                float z2 = tval * (ath - D);
                float wgt = 1.0f / (1.0f + __expf(-z2));
                wob[(size_t)m * NTOK + n0 + ct * 16 + lm] = wgt;
            }
        }
}

extern "C" void kernel_launch(void* const* d_in, const int* in_sizes, int n_in,
                              void* d_out, int out_size, void* d_ws, size_t ws_size,
                              hipStream_t stream) {
    const float* x    = (const float*)d_in[0];   // [2,2048,128] f32
    const float* A    = (const float*)d_in[1];   // [2,2048,2048] f32
    const float* W    = (const float*)d_in[2];   // [128,64] f32
    const float* bvec = (const float*)d_in[3];   // [64] f32
    const float* temp = (const float*)d_in[4];   // scalar f32
    const float* thr  = (const float*)d_in[5];   // scalar f32
    float* out = (float*)d_out;                  // x_emb | edge_index | weights
    char* ws = (char*)d_ws;

    unsigned short* XwT  = (unsigned short*)(ws + 0);        // 64x4096 bf16 (512 KB)
    float*          cent = (float*)(ws + 524288);            // 128 f32
    unsigned*       mx   = (unsigned*)(ws + 524800);         // 1 u32
    unsigned short* xebf = (unsigned short*)(ws + 524816);   // 4096x64 bf16 (512 KB)
    float*          q    = (float*)(ws + 1049104);           // 4096 f32

    float* xemb_out = out;                       // [0, 262144)
    float* edge_out = out + 262144;              // [262144, 17039360)
    float* wgt_out  = out + 262144 + 16777216;   // [17039360, 25427968)

    k_gemm_xwT<<<128, 256, 0, stream>>>(x, W, XwT, (unsigned*)(ws + 524288));
    k_gemm_xemb<<<dim3(128, 2), 512, 0, stream>>>(A, XwT, bvec, xemb_out, xebf, q, cent);
    k_maxabs<<<256, 256, 0, stream>>>(xemb_out, cent, mx);
    k_adj_edges<<<dim3(16, 16, 4), 256, 0, stream>>>(xebf, q, mx, temp, thr,
                                                     wgt_out, edge_out);
}

// Round 5
// 155.088 us; speedup vs baseline: 1.2778x; 1.0929x over previous
//
#include <hip/hip_runtime.h>

#define NTOK 2048
#define BATCH 2
#define FIN 128
#define FEMB 64

typedef __attribute__((ext_vector_type(8))) short short8;
typedef __attribute__((ext_vector_type(4))) float floatx4;

#define MFMA_B16(a, b, c) __builtin_amdgcn_mfma_f32_16x16x32_bf16((a), (b), (c), 0, 0, 0)

// f32 -> bf16 bits (RNE)
static __device__ __forceinline__ unsigned short f2bf_bits(float f) {
    unsigned u = __float_as_uint(f);
    unsigned r = u + 0x7FFFu + ((u >> 16) & 1u);
    return (unsigned short)(r >> 16);
}
static __device__ __forceinline__ float bfbits2f(unsigned short h) {
    return __uint_as_float(((unsigned)h) << 16);
}

// ws stat block layout (uints): [0,128) cent f32-as-bits via atomicAdd(float*),
// [128,256) colmin (init +inf), [256,384) colmax (init 0)
// ============ K1: XwT[64][4096] = bf16(W)^T (64x128) @ bf16(x)^T (128x4096) =
// n-tile 32, grid 128. Block 0 zero-inits the stat block (runs before K2).
#define K1S 152   // 128+24 shorts: rows differ by 12 dword-banks -> <=2-way, free
__global__ __launch_bounds__(256) void k_gemm_xwT(const float* __restrict__ x,
                                                  const float* __restrict__ W,
                                                  unsigned short* __restrict__ XwT,
                                                  unsigned* __restrict__ stats) {
    __shared__ unsigned short As[64 * K1S];   // WT[f][k]
    __shared__ unsigned short Bs[32 * K1S];   // x token rows [n][k]
    int t = threadIdx.x;
    int n0 = blockIdx.x * 32;
    if (blockIdx.x == 0 && t < 384)
        stats[t] = (t >= 128 && t < 256) ? 0x7F800000u : 0u;   // cent=0, min=+inf, max=0
    // W: 128x64 f32 (L2-resident) -> transposed bf16 in LDS
#pragma unroll
    for (int c = 0; c < 32; ++c) {
        int idx = c * 256 + t;
        int k = idx >> 6, f = idx & 63;
        As[f * K1S + k] = f2bf_bits(W[idx]);
    }
    // x tile: 32 tokens x 128 feat f32 -> bf16
#pragma unroll
    for (int c = 0; c < 2; ++c) {
        int e = c * 2048 + t * 8;
        int row = e >> 7, col = e & 127;
        const float* src = &x[(size_t)(n0 + row) * FIN + col];
        float4 f0 = *(const float4*)src;
        float4 f1 = *(const float4*)(src + 4);
        unsigned short h[8] = {f2bf_bits(f0.x), f2bf_bits(f0.y), f2bf_bits(f0.z),
                               f2bf_bits(f0.w), f2bf_bits(f1.x), f2bf_bits(f1.y),
                               f2bf_bits(f1.z), f2bf_bits(f1.w)};
        *(uint4*)&Bs[row * K1S + col] = *(uint4*)h;
    }
    __syncthreads();
    int w = t >> 6, l = t & 63, lm = l & 15, lq = l >> 4;
    floatx4 acc[2] = {};
#pragma unroll
    for (int kk = 0; kk < 128; kk += 32) {
        short8 a = *(const short8*)&As[(w * 16 + lm) * K1S + kk + lq * 8];
#pragma unroll
        for (int ct = 0; ct < 2; ++ct) {
            short8 b = *(const short8*)&Bs[(ct * 16 + lm) * K1S + kk + lq * 8];
            acc[ct] = MFMA_B16(a, b, acc[ct]);
        }
    }
#pragma unroll
    for (int ct = 0; ct < 2; ++ct)
#pragma unroll
        for (int r = 0; r < 4; ++r) {
            int f = w * 16 + lq * 4 + r;
            int tok = n0 + ct * 16 + lm;
            XwT[(size_t)f * (BATCH * NTOK) + tok] = f2bf_bits(acc[ct][r]);
        }
}

// ============ K2: x_emb = relu(A @ Xw + b); LDS-free streaming GEMM =========
// 512 thr (8 waves), each wave owns K-range w*256..+256; no barriers in loop.
// Epilogue: cross-wave f32 reduce in LDS; emit xemb f32 + bf16, q rowsums,
// centroid atomicAdd + column min/max atomics (for the scale). grid (128, 2).
#define RP 66     // 64+2 f32: wave-partial row stride (2-way banks, free)
__global__ __launch_bounds__(512) void k_gemm_xemb(const float* __restrict__ A,
                                                   const unsigned short* __restrict__ XwT,
                                                   const float* __restrict__ bvec,
                                                   float* __restrict__ xemb_out,
                                                   unsigned short* __restrict__ xebf,
                                                   float* __restrict__ q,
                                                   unsigned* __restrict__ stats) {
    __shared__ float red[8][16][RP];   // 33.8 KB
    int t = threadIdx.x;
    int m0 = blockIdx.x * 16, b = blockIdx.y;
    int w = t >> 6, l = t & 63, lm = l & 15, lq = l >> 4;
    const float* Arow =
        A + (size_t)b * NTOK * NTOK + (size_t)(m0 + lm) * NTOK + w * 256 + lq * 8;
    const unsigned short* Bbase = XwT + b * NTOK + w * 256 + lq * 8;  // + f*4096
    floatx4 acc[4] = {};
#pragma unroll
    for (int kk = 0; kk < 256; kk += 32) {
        float4 a0 = *(const float4*)(Arow + kk);
        float4 a1 = *(const float4*)(Arow + kk + 4);
        unsigned short h[8] = {f2bf_bits(a0.x), f2bf_bits(a0.y), f2bf_bits(a0.z),
                               f2bf_bits(a0.w), f2bf_bits(a1.x), f2bf_bits(a1.y),
                               f2bf_bits(a1.z), f2bf_bits(a1.w)};
        short8 af = *(short8*)h;
#pragma unroll
        for (int ct = 0; ct < 4; ++ct) {
            short8 bf = *(const short8*)(Bbase + (size_t)(ct * 16 + lm) * (BATCH * NTOK) + kk);
            acc[ct] = MFMA_B16(af, bf, acc[ct]);
        }
    }
#pragma unroll
    for (int ct = 0; ct < 4; ++ct)
#pragma unroll
        for (int r = 0; r < 4; ++r)
            red[w][lq * 4 + r][ct * 16 + lm] = acc[ct][r];
    __syncthreads();
    // thread t: row r = t>>5 (16 rows), cols c0 = (t&31)*2 (+1)
    int r = t >> 5, c0 = (t & 31) * 2;
    float v0 = 0.f, v1 = 0.f;
#pragma unroll
    for (int ww = 0; ww < 8; ++ww) {
        v0 += red[ww][r][c0];
        v1 += red[ww][r][c0 + 1];
    }
    v0 = fmaxf(v0 + bvec[c0], 0.0f);
    v1 = fmaxf(v1 + bvec[c0 + 1], 0.0f);
    size_t o = (size_t)b * NTOK * FEMB + (size_t)(m0 + r) * FEMB + c0;
    *(float2*)&xemb_out[o] = make_float2(v0, v1);
    unsigned short h0 = f2bf_bits(v0), h1 = f2bf_bits(v1);
    *(unsigned*)&xebf[o] = (unsigned)h0 | ((unsigned)h1 << 16);
    float d0 = bfbits2f(h0), d1 = bfbits2f(h1);
    float s = d0 * d0 + d1 * d1;   // row-sumsq partial (2 cols)
#pragma unroll
    for (int off = 16; off; off >>= 1) s += __shfl_xor(s, off, 64);  // 32-lane group
    if ((t & 31) == 0) q[b * NTOK + m0 + r] = s;
    __syncthreads();               // red reads done; reuse red[0] as vb[16][RP]
    red[0][r][c0] = v0;
    red[0][r][c0 + 1] = v1;
    __syncthreads();
    if (t < 64) {
        float cs = 0.f, mn = red[0][0][t], mxv = mn;
#pragma unroll
        for (int rr = 0; rr < 16; ++rr) {
            float v = red[0][rr][t];
            cs += v;
            mn = fminf(mn, v);
            mxv = fmaxf(mxv, v);
        }
        atomicAdd((float*)&stats[b * 64 + t], cs);          // centroid sum
        atomicMin(&stats[128 + b * 64 + t], __float_as_uint(mn));   // v>=0: bit-monotone
        atomicMax(&stats[256 + b * 64 + t], __float_as_uint(mxv));
    }
}

// ============ K3: adjacency (z<2) + edge_index (z>=2) fused =================
// D = s^2 * relu(q_m + q_n - 2<e_m,e_n>)  (centroid cancels; s = 0.9/mx,
// mx = max_{b,f} max(colmax-c, c-colmin) computed inline from stats)
#define K5S 88
__global__ __launch_bounds__(256) void k_adj_edges(const unsigned short* __restrict__ xebf,
                                                   const float* __restrict__ q,
                                                   const unsigned* __restrict__ stats,
                                                   const float* __restrict__ temp,
                                                   const float* __restrict__ thr,
                                                   float* __restrict__ wout,
                                                   float* __restrict__ eout) {
    int z = blockIdx.z;
    if (z >= 2) {   // ---- edge_index: 16,777,216 f32 over 512 blocks ----
        int eb = (z - 2) * 256 + blockIdx.y * 16 + blockIdx.x;
        long base0 = (long)eb * 32768 + threadIdx.x * 4;
#pragma unroll
        for (int j = 0; j < 32; ++j) {
            long g = base0 + (long)j * 1024;
            float4 v;
            if (g < 8388608L) {                  // rows: idx // N (const over 4)
                float rr = (float)(g >> 11);
                v.x = rr; v.y = rr; v.z = rr; v.w = rr;
            } else {                             // cols: idx % N + N*batch
                long rel = g - 8388608L;
                int c0 = (int)(rel & 2047);      // 4-aligned, no wrap
                int add = ((int)(rel >> 22)) << 11;
                v.x = (float)(c0 + 0 + add);
                v.y = (float)(c0 + 1 + add);
                v.z = (float)(c0 + 2 + add);
                v.w = (float)(c0 + 3 + add);
            }
            *(float4*)&eout[g] = v;
        }
        return;
    }
    // ---- adjacency: 128x128 tile, K=64 single shot ----
    __shared__ unsigned short As[128 * K5S];
    __shared__ unsigned short Bs[128 * K5S];
    int t = threadIdx.x;
    int m0 = blockIdx.x * 128, n0 = blockIdx.y * 128, b = z;
    // inline global scale from stats (per-wave redundant, no barrier)
    float sc;
    {
        int l = t & 63;
        float m = 0.f;
#pragma unroll
        for (int b2 = 0; b2 < 2; ++b2) {
            float c = __uint_as_float(stats[b2 * 64 + l]) * (1.0f / NTOK);
            float hi = __uint_as_float(stats[256 + b2 * 64 + l]);
            float lo = __uint_as_float(stats[128 + b2 * 64 + l]);
            m = fmaxf(m, fmaxf(hi - c, c - lo));
        }
#pragma unroll
        for (int off = 32; off; off >>= 1) m = fmaxf(m, __shfl_xor(m, off, 64));
        sc = 0.9f / m;
    }
    float s2 = sc * sc;
    const unsigned short* xb = xebf + (size_t)b * NTOK * FEMB;
#pragma unroll
    for (int c = 0; c < 4; ++c) {
        int e = c * 2048 + t * 8;
        int row = e >> 6, col = e & 63;
        *(uint4*)&As[row * K5S + col] = *(const uint4*)&xb[(size_t)(m0 + row) * FEMB + col];
        *(uint4*)&Bs[row * K5S + col] = *(const uint4*)&xb[(size_t)(n0 + row) * FEMB + col];
    }
    __syncthreads();
    int w = t >> 6, l = t & 63, lm = l & 15, lq = l >> 4;
    floatx4 acc[2][8] = {};
#pragma unroll
    for (int kk = 0; kk < 64; kk += 32) {
        short8 a0 = *(const short8*)&As[((w * 2 + 0) * 16 + lm) * K5S + kk + lq * 8];
        short8 a1 = *(const short8*)&As[((w * 2 + 1) * 16 + lm) * K5S + kk + lq * 8];
#pragma unroll
        for (int ct = 0; ct < 8; ++ct) {
            short8 bb = *(const short8*)&Bs[(ct * 16 + lm) * K5S + kk + lq * 8];
            acc[0][ct] = MFMA_B16(a0, bb, acc[0][ct]);
            acc[1][ct] = MFMA_B16(a1, bb, acc[1][ct]);
        }
    }
    float tval = temp[0];
    float ath = fabsf(thr[0]);
    float qm[2][4], qn[8];
#pragma unroll
    for (int rt = 0; rt < 2; ++rt)
#pragma unroll
        for (int r = 0; r < 4; ++r)
            qm[rt][r] = q[b * NTOK + m0 + (w * 2 + rt) * 16 + lq * 4 + r];
#pragma unroll
    for (int ct = 0; ct < 8; ++ct) qn[ct] = q[b * NTOK + n0 + ct * 16 + lm];
    float* wob = wout + (size_t)b * NTOK * NTOK;
#pragma unroll
    for (int rt = 0; rt < 2; ++rt)
#pragma unroll
        for (int r = 0; r < 4; ++r) {
            int m = m0 + (w * 2 + rt) * 16 + lq * 4 + r;
#pragma unroll
            for (int ct = 0; ct < 8; ++ct) {
                float g = acc[rt][ct][r];
                float D = s2 * fmaxf(qm[rt][r] + qn[ct] - 2.0f * g, 0.0f);
                float z2 = tval * (ath - D);
                float wgt = 1.0f / (1.0f + __expf(-z2));
                wob[(size_t)m * NTOK + n0 + ct * 16 + lm] = wgt;
            }
        }
}

extern "C" void kernel_launch(void* const* d_in, const int* in_sizes, int n_in,
                              void* d_out, int out_size, void* d_ws, size_t ws_size,
                              hipStream_t stream) {
    const float* x    = (const float*)d_in[0];   // [2,2048,128] f32
    const float* A    = (const float*)d_in[1];   // [2,2048,2048] f32
    const float* W    = (const float*)d_in[2];   // [128,64] f32
    const float* bvec = (const float*)d_in[3];   // [64] f32
    const float* temp = (const float*)d_in[4];   // scalar f32
    const float* thr  = (const float*)d_in[5];   // scalar f32
    float* out = (float*)d_out;                  // x_emb | edge_index | weights
    char* ws = (char*)d_ws;

    unsigned short* XwT   = (unsigned short*)(ws + 0);        // 64x4096 bf16 (512 KB)
    unsigned*       stats = (unsigned*)(ws + 524288);         // cent|min|max (384 u32)
    unsigned short* xebf  = (unsigned short*)(ws + 525824);   // 4096x64 bf16 (512 KB)
    float*          q     = (float*)(ws + 1050112);           // 4096 f32

    float* xemb_out = out;                       // [0, 262144)
    float* edge_out = out + 262144;              // [262144, 17039360)
    float* wgt_out  = out + 262144 + 16777216;   // [17039360, 25427968)

    k_gemm_xwT<<<128, 256, 0, stream>>>(x, W, XwT, stats);
    k_gemm_xemb<<<dim3(128, 2), 512, 0, stream>>>(A, XwT, bvec, xemb_out, xebf, q, stats);
    k_adj_edges<<<dim3(16, 16, 4), 256, 0, stream>>>(xebf, q, stats, temp, thr,
                                                     wgt_out, edge_out);
}